// Round 1
// baseline (133.323 us; speedup 1.0000x reference)
//
#include <hip/hip_runtime.h>
#include <hip/hip_bf16.h>

typedef unsigned short u16;
typedef __bf16 bf16x8 __attribute__((ext_vector_type(8)));
typedef float f32x4 __attribute__((ext_vector_type(4)));
typedef u16 u16x4 __attribute__((ext_vector_type(4)));

#define B_ 2
#define L_ 2048
#define D_ 128
#define KLAY 3
#define NR 16
#define NATOM 118

static __device__ __forceinline__ u16 f2bf(float f) {
    union { float f; unsigned u; } v; v.f = f;
    unsigned r = v.u + 0x7FFFu + ((v.u >> 16) & 1u);
    return (u16)(r >> 16);
}
static __device__ __forceinline__ bf16x8 ld_bf8(const u16* p) {
    return *(const bf16x8*)p;
}

// ---------------- prep: transpose weights to bf16 [n][k] layouts ----------------
__global__ __launch_bounds__(256) void prep_kernel(
    const float* atom_emb, const float* out_w, const float* self_w,
    const float* msg_w, const float* upd_w,
    u16* atom16, u16* outwT, u16* selfT, u16* msgT, u16* updT) {
    const int T0 = NATOM * D_;          // atom cvt
    const int T1 = D_ * 2 * D_;         // outwT[n][k] n<128 k<256
    const int T2 = KLAY * D_ * D_;      // selfT
    const int T3 = KLAY * D_ * D_;      // msgT
    const int T4 = KLAY * D_ * 2 * D_;  // updT[kk][n][k] n<128 k<256
    int total = T0 + T1 + T2 + T3 + T4;
    for (int t = blockIdx.x * blockDim.x + threadIdx.x; t < total;
         t += gridDim.x * blockDim.x) {
        int u = t;
        if (u < T0) { atom16[u] = f2bf(atom_emb[u]); continue; }
        u -= T0;
        if (u < T1) {
            int n = u / (2 * D_), k = u % (2 * D_);
            outwT[u] = f2bf(out_w[k * D_ + n]);
            continue;
        }
        u -= T1;
        if (u < T2) {
            int kk = u / (D_ * D_), v = u % (D_ * D_);
            int n = v / D_, k = v % D_;
            selfT[u] = f2bf(self_w[kk * D_ * D_ + k * D_ + n]);
            continue;
        }
        u -= T2;
        if (u < T3) {
            int kk = u / (D_ * D_), v = u % (D_ * D_);
            int n = v / D_, k = v % D_;
            msgT[u] = f2bf(msg_w[kk * D_ * D_ + k * D_ + n]);
            continue;
        }
        u -= T3;
        {
            int kk = u / (D_ * 2 * D_), v = u % (D_ * 2 * D_);
            int n = v / (2 * D_), k = v % (2 * D_);
            updT[u] = f2bf(upd_w[kk * 2 * D_ * D_ + k * D_ + n]);
        }
    }
}

// ---------------- pairwise: W16 = bf16(exp(-dist)), rbf_local mean ----------------
__global__ __launch_bounds__(256) void pairwise_kernel(
    const float* coords, const float* gamma_p, const float* centers,
    u16* W16, float* rbf_loc) {
    int bi = blockIdx.x;  // b*L + i
    int b = bi >> 11;
    int tid = threadIdx.x;
    float gamma = gamma_p[0];
    __shared__ float cen[NR];
    if (tid < NR) cen[tid] = centers[tid];
    float cx = coords[bi * 3 + 0];
    float cy = coords[bi * 3 + 1];
    float cz = coords[bi * 3 + 2];
    float acc[NR];
#pragma unroll
    for (int r = 0; r < NR; r++) acc[r] = 0.f;
    __syncthreads();
    const float* cb = coords + (size_t)b * L_ * 3;
    u16* wrow = W16 + (size_t)bi * L_;
    for (int jj = 0; jj < L_; jj += 256) {
        int j = jj + tid;
        float dx = cx - cb[j * 3 + 0];
        float dy = cy - cb[j * 3 + 1];
        float dz = cz - cb[j * 3 + 2];
        float sq = dx * dx + dy * dy + dz * dz;
        float d = sq > 0.f ? sqrtf(sq) : 0.f;
        wrow[j] = f2bf(__expf(-d));
#pragma unroll
        for (int r = 0; r < NR; r++) {
            float t = d - cen[r];
            acc[r] += __expf(-gamma * t * t);
        }
    }
    __shared__ float red[256][NR + 1];
#pragma unroll
    for (int r = 0; r < NR; r++) red[tid][r] = acc[r];
    __syncthreads();
    for (int s = 128; s > 0; s >>= 1) {
        if (tid < s) {
#pragma unroll
            for (int r = 0; r < NR; r++) red[tid][r] += red[tid + s][r];
        }
        __syncthreads();
    }
    if (tid < NR) rbf_loc[(size_t)bi * NR + tid] = red[0][tid] * (1.0f / L_);
}

// ---------------- encoder: h16 = cat(atom_emb[Z], h_geo) @ out_w + out_b ----------------
__global__ __launch_bounds__(256) void encoder_kernel(
    const int* Z, const float* rbf_w, const float* rbf_b, const float* out_b,
    const float* rbf_loc, const u16* atom16, const u16* outwT, u16* h16) {
    int gi0 = blockIdx.x * 16;
    int tid = threadIdx.x;
    __shared__ __align__(16) u16 hgeo[16][136];  // +8 pad
    for (int e = tid; e < 16 * D_; e += 256) {
        int row = e >> 7, d = e & 127;
        int gi = gi0 + row;
        float s = rbf_b[d];
#pragma unroll
        for (int r = 0; r < NR; r++)
            s += rbf_loc[(size_t)gi * NR + r] * rbf_w[r * D_ + d];
        hgeo[row][d] = f2bf(s);
    }
    __syncthreads();
    int w = tid >> 6, lane = tid & 63;
    int rowf = lane & 15, kg = lane >> 4;
    f32x4 acc[2] = {{0.f, 0.f, 0.f, 0.f}, {0.f, 0.f, 0.f, 0.f}};
    int za = Z[gi0 + rowf];
    for (int ks = 0; ks < 8; ks++) {
        int k0 = ks * 32 + kg * 8;
        bf16x8 a;
        if (k0 < 128) a = ld_bf8(atom16 + za * D_ + k0);
        else a = ld_bf8(&hgeo[rowf][k0 - 128]);
#pragma unroll
        for (int q = 0; q < 2; q++) {
            int col = (w * 2 + q) * 16 + rowf;
            bf16x8 bb = ld_bf8(outwT + col * (2 * D_) + k0);
            acc[q] = __builtin_amdgcn_mfma_f32_16x16x32_bf16(a, bb, acc[q], 0, 0, 0);
        }
    }
#pragma unroll
    for (int q = 0; q < 2; q++) {
        int col = (w * 2 + q) * 16 + rowf;
        float bias = out_b[col];
#pragma unroll
        for (int r = 0; r < 4; r++) {
            int row = kg * 4 + r;
            h16[(size_t)(gi0 + row) * D_ + col] = f2bf(acc[q][r] + bias);
        }
    }
}

// ---------------- per-layer: S = h@self_w+b (row-major), X^T = (h@msg_w+b)^T ----------------
__global__ __launch_bounds__(256) void sx_kernel(
    const u16* h16, const u16* selfT_k, const u16* msgT_k,
    const float* self_b_k, const float* msg_b_k, u16* S16, u16* XT16) {
    int gi0 = blockIdx.x * 16;
    int tid = threadIdx.x;
    int w = tid >> 6, lane = tid & 63;
    int rowf = lane & 15, kg = lane >> 4;
    f32x4 z = {0.f, 0.f, 0.f, 0.f};
    f32x4 acc[4] = {z, z, z, z};
    for (int ks = 0; ks < 4; ks++) {
        int k0 = ks * 32 + kg * 8;
        bf16x8 a = ld_bf8(h16 + (size_t)(gi0 + rowf) * D_ + k0);
#pragma unroll
        for (int q = 0; q < 4; q++) {
            int nb = w * 4 + q;  // 0..15
            const u16* wp = (nb < 8) ? (selfT_k + (nb * 16 + rowf) * D_ + k0)
                                     : (msgT_k + ((nb - 8) * 16 + rowf) * D_ + k0);
            bf16x8 bb = ld_bf8(wp);
            acc[q] = __builtin_amdgcn_mfma_f32_16x16x32_bf16(a, bb, acc[q], 0, 0, 0);
        }
    }
    int b = gi0 >> 11;
    int il0 = gi0 & (L_ - 1);
#pragma unroll
    for (int q = 0; q < 4; q++) {
        int nb = w * 4 + q;
        if (nb < 8) {
            int cl = nb * 16 + rowf;
            float bias = self_b_k[cl];
#pragma unroll
            for (int r = 0; r < 4; r++) {
                int row = kg * 4 + r;
                S16[(size_t)(gi0 + row) * D_ + cl] = f2bf(acc[q][r] + bias);
            }
        } else {
            int cl = (nb - 8) * 16 + rowf;
            float bias = msg_b_k[cl];
            u16x4 pk;
#pragma unroll
            for (int r = 0; r < 4; r++) pk[r] = f2bf(acc[q][r] + bias);
            *(u16x4*)(XT16 + ((size_t)(b * D_ + cl)) * L_ + il0 + kg * 4) = pk;
        }
    }
}

// ---------------- per-layer MP: msg = W@X ; h' = S@U_top + msg@U_bot + b ----------------
__global__ __launch_bounds__(256) void mp_kernel(
    const u16* W16, const u16* XT16, const u16* S16, const u16* updT_k,
    const float* upd_b_k, u16* h16_out, float* out_f32, int last) {
    int gi0 = blockIdx.x * 16;
    int b = gi0 >> 11;
    int il0 = gi0 & (L_ - 1);
    int tid = threadIdx.x;
    int w = tid >> 6, lane = tid & 63;
    int rowf = lane & 15, kg = lane >> 4;
    f32x4 z = {0.f, 0.f, 0.f, 0.f};
    f32x4 acc[8] = {z, z, z, z, z, z, z, z};
    // wave w handles j in [w*512, (w+1)*512)
    const u16* wbase = W16 + ((size_t)(b * L_ + il0 + rowf)) * L_ + w * 512 + kg * 8;
    const u16* xbase = XT16 + (size_t)b * D_ * L_ + w * 512 + kg * 8;
    for (int s = 0; s < 16; s++) {
        int j8 = s * 32;
        bf16x8 a = ld_bf8(wbase + j8);
#pragma unroll
        for (int n = 0; n < 8; n++) {
            bf16x8 bb = ld_bf8(xbase + (size_t)(n * 16 + rowf) * L_ + j8);
            acc[n] = __builtin_amdgcn_mfma_f32_16x16x32_bf16(a, bb, acc[n], 0, 0, 0);
        }
    }
    // cross-wave K reduction in LDS
    __shared__ float red[4][16][132];
#pragma unroll
    for (int n = 0; n < 8; n++)
#pragma unroll
        for (int r = 0; r < 4; r++)
            red[w][kg * 4 + r][n * 16 + rowf] = acc[n][r];
    __syncthreads();
    // epilogue: out = S@U_top + msg@U_bot + bias
    f32x4 acc2[2] = {z, z};
    for (int ks = 0; ks < 4; ks++) {
        int k0 = ks * 32 + kg * 8;
        bf16x8 a_s = ld_bf8(S16 + (size_t)(gi0 + rowf) * D_ + k0);
        union { bf16x8 v; u16 s[8]; } am;
#pragma unroll
        for (int e = 0; e < 8; e++) {
            float m = red[0][rowf][k0 + e] + red[1][rowf][k0 + e] +
                      red[2][rowf][k0 + e] + red[3][rowf][k0 + e];
            am.s[e] = f2bf(m);
        }
#pragma unroll
        for (int q = 0; q < 2; q++) {
            int cl = (w * 2 + q) * 16 + rowf;
            bf16x8 b_s = ld_bf8(updT_k + cl * (2 * D_) + k0);
            bf16x8 b_m = ld_bf8(updT_k + cl * (2 * D_) + 128 + k0);
            acc2[q] = __builtin_amdgcn_mfma_f32_16x16x32_bf16(a_s, b_s, acc2[q], 0, 0, 0);
            acc2[q] = __builtin_amdgcn_mfma_f32_16x16x32_bf16(am.v, b_m, acc2[q], 0, 0, 0);
        }
    }
#pragma unroll
    for (int q = 0; q < 2; q++) {
        int cl = (w * 2 + q) * 16 + rowf;
        float bias = upd_b_k[cl];
#pragma unroll
        for (int r = 0; r < 4; r++) {
            int row = kg * 4 + r;
            float v = acc2[q][r] + bias;
            if (last) out_f32[(size_t)(gi0 + row) * D_ + cl] = v;
            else h16_out[(size_t)(gi0 + row) * D_ + cl] = f2bf(v);
        }
    }
}

extern "C" void kernel_launch(void* const* d_in, const int* in_sizes, int n_in,
                              void* d_out, int out_size, void* d_ws, size_t ws_size,
                              hipStream_t stream) {
    const float* coords = (const float*)d_in[0];
    const int* Z = (const int*)d_in[1];
    const float* atom_emb = (const float*)d_in[2];
    const float* gamma = (const float*)d_in[3];
    const float* centers = (const float*)d_in[4];
    const float* rbf_w = (const float*)d_in[5];
    const float* rbf_b = (const float*)d_in[6];
    const float* out_w = (const float*)d_in[7];
    const float* out_b = (const float*)d_in[8];
    const float* self_w = (const float*)d_in[9];
    const float* self_b = (const float*)d_in[10];
    const float* msg_w = (const float*)d_in[11];
    const float* msg_b = (const float*)d_in[12];
    const float* upd_w = (const float*)d_in[13];
    const float* upd_b = (const float*)d_in[14];
    float* out = (float*)d_out;

    char* ws = (char*)d_ws;
    // ws layout (bytes), ~20.7 MB total
    u16* W16 = (u16*)(ws + 0);              // 16,777,216
    u16* h16 = (u16*)(ws + 16777216);       // 1,048,576
    u16* S16 = (u16*)(ws + 17825792);       // 1,048,576
    u16* XT16 = (u16*)(ws + 18874368);      // 1,048,576
    float* rbfl = (float*)(ws + 19922944);  // 262,144
    u16* atom16 = (u16*)(ws + 20185088);    // 30,208 (pad to 32,768)
    u16* outwT = (u16*)(ws + 20217856);     // 65,536
    u16* selfT = (u16*)(ws + 20283392);     // 98,304
    u16* msgT = (u16*)(ws + 20381696);      // 98,304
    u16* updT = (u16*)(ws + 20480000);      // 196,608

    prep_kernel<<<64, 256, 0, stream>>>(atom_emb, out_w, self_w, msg_w, upd_w,
                                        atom16, outwT, selfT, msgT, updT);
    pairwise_kernel<<<B_ * L_, 256, 0, stream>>>(coords, gamma, centers, W16, rbfl);
    encoder_kernel<<<(B_ * L_) / 16, 256, 0, stream>>>(Z, rbf_w, rbf_b, out_b, rbfl,
                                                       atom16, outwT, h16);
    for (int k = 0; k < KLAY; k++) {
        sx_kernel<<<(B_ * L_) / 16, 256, 0, stream>>>(
            h16, selfT + k * D_ * D_, msgT + k * D_ * D_, self_b + k * D_,
            msg_b + k * D_, S16, XT16);
        mp_kernel<<<(B_ * L_) / 16, 256, 0, stream>>>(
            W16, XT16, S16, updT + k * D_ * 2 * D_, upd_b + k * D_, h16, out,
            k == KLAY - 1 ? 1 : 0);
    }
}